// Round 9
// baseline (200.037 us; speedup 1.0000x reference)
//
#include <hip/hip_runtime.h>
#include <hip/hip_bf16.h>

// Problem constants (fixed by setup_inputs)
#define E_TOTAL 262144
#define NG      128
#define GRAPHS  64
#define NHEADS  8
#define DKH     64
#define DMODEL  512
#define NNODES  8192

typedef __bf16 bf16x8 __attribute__((ext_vector_type(8)));
typedef __bf16 bf16x4 __attribute__((ext_vector_type(4)));
typedef float  f32x4  __attribute__((ext_vector_type(4)));
typedef short  s16x4  __attribute__((ext_vector_type(4)));

typedef __attribute__((address_space(3))) char lds_char;
typedef const __attribute__((address_space(1))) char glb_char;

__device__ inline __hip_bfloat16 f2hbf(float f) { return __float2bfloat16(f); }
__device__ inline unsigned short f2u16(float f) {
    return __builtin_bit_cast(unsigned short, __float2bfloat16(f));
}
__device__ inline __bf16 f2bf(float f) {
    return __builtin_bit_cast(__bf16, f2u16(f));
}
__device__ inline bf16x8 cvt8(float4 lo, float4 hi) {
    bf16x8 o;
    o[0] = f2bf(lo.x); o[1] = f2bf(lo.y); o[2] = f2bf(lo.z); o[3] = f2bf(lo.w);
    o[4] = f2bf(hi.x); o[5] = f2bf(hi.y); o[6] = f2bf(hi.z); o[7] = f2bf(hi.w);
    return o;
}

// ---------------------------------------------------------------------------
// Prep: weight transpose/cast + edge-MLP frag tables + x fp32->bf16 pre-pass.
// ---------------------------------------------------------------------------
__global__ __launch_bounds__(256) void prep_kernel(
    const float* __restrict__ Wq, const float* __restrict__ Wk,
    const float* __restrict__ Wv, const float* __restrict__ Wo,
    const float* __restrict__ W1, const float* __restrict__ b1,
    const float* __restrict__ W2, const float* __restrict__ b2,
    const float* __restrict__ x, __hip_bfloat16* __restrict__ xbf,
    __hip_bfloat16* __restrict__ wqkvt, __hip_bfloat16* __restrict__ wot,
    __hip_bfloat16* __restrict__ w1fragt, float* __restrict__ b1f,
    __hip_bfloat16* __restrict__ w2at, float* __restrict__ b2f)
{
    int blk = blockIdx.x, tid = threadIdx.x;
    if (blk < 256) {
        __shared__ __align__(16) __hip_bfloat16 tile[64][65];
        const float* src;
        __hip_bfloat16* dstT;
        int n0, k0, nb;
        if (blk < 192) {
            int nt = blk % 24, ktile = blk / 24;
            n0 = nt * 64; k0 = ktile * 64;
            if (n0 < 512)       { src = Wq; nb = n0; }
            else if (n0 < 1024) { src = Wk; nb = n0 - 512; }
            else                { src = Wv; nb = n0 - 1024; }
            dstT = wqkvt;
        } else {
            int t = blk - 192;
            n0 = (t % 8) * 64; k0 = (t / 8) * 64; nb = n0;
            src = Wo; dstT = wot;
        }
        #pragma unroll
        for (int i = 0; i < 16; ++i) {
            int idx = tid + i * 256;
            int kr = idx >> 6, nc = idx & 63;
            tile[kr][nc] = f2hbf(src[(size_t)(k0 + kr) * 512 + nb + nc]);
        }
        __syncthreads();
        #pragma unroll
        for (int i = 0; i < 16; ++i) {
            int idx = tid + i * 256;
            int nr = idx >> 6, kc = idx & 63;
            dstT[(size_t)(n0 + nr) * 512 + k0 + kc] = tile[kc][nr];
        }
    } else if (blk == 256) {
        __hip_bfloat16 z = f2hbf(0.f);
        // w1fragt: [512][4] (K=16 MFMA A-frag)
        for (int n = tid; n < 512; n += 256) {
            #pragma unroll
            for (int j = 0; j < 4; ++j) w1fragt[n * 4 + j] = f2hbf(W1[(size_t)j * 512 + n]);
        }
        for (int i = tid; i < 512; i += 256) b1f[i] = b1[i];
        // w2at: [32][64][4], W2 is (512,8) row-major
        for (int i = tid; i < 32 * 64 * 4; i += 256) {
            int t = i >> 8, lane = (i >> 2) & 63, j = i & 3;
            int q = lane >> 4, l = lane & 15;
            w2at[i] = (l < 8) ? f2hbf(W2[(size_t)(16 * t + 4 * q + j) * 8 + l]) : z;
        }
        if (tid < 8) b2f[tid] = b2[tid];
    } else {
        // x -> bf16, 2048 elems per block (8 per thread)
        int base = (blk - 257) * 2048 + tid * 8;
        float4 lo = *(const float4*)(x + base);
        float4 hi = *(const float4*)(x + base + 4);
        *(bf16x8*)(xbf + base) = cvt8(lo, hi);
    }
}

// ---------------------------------------------------------------------------
// QKV GEMM body, 128x128 tile, now 512 THREADS (8 waves, 4x2 wave grid,
// 32x64 sub-tile per wave, acc[2][4]). Same LDS (48KB, 3-buf) and barrier
// count as the 256-thread version, but: 24 waves/CU capacity (was 12),
// 2 global_load_lds per thread per K-step (was 4, vmcnt(2) steady), and
// half the acc VGPR. Occupancy is the R9 lever: 22% measured was the cap.
// QKPATH=true: swapped MFMA operands -> lane holds 4 consecutive d-dims.
// ---------------------------------------------------------------------------
template <bool QKPATH>
__device__ __forceinline__ void gemm0_body(
    const __hip_bfloat16* __restrict__ A, const __hip_bfloat16* __restrict__ BT,
    int row0, int col0,
    const float* __restrict__ bq, const float* __restrict__ bk,
    const float* __restrict__ bv,
    __hip_bfloat16* __restrict__ qbuf, __hip_bfloat16* __restrict__ kbuf,
    __hip_bfloat16* __restrict__ vt,
    __hip_bfloat16* __restrict__ As, __hip_bfloat16* __restrict__ Bs)
{
    const int K = 512;
    int tid = threadIdx.x;                 // 0..511
    int lane = tid & 63, quad = lane >> 4, l16 = lane & 15;
    int wave = tid >> 6;                   // 0..7
    int wi = wave >> 1, wj = wave & 1;     // 4 x 2 wave grid

    f32x4 acc[2][4];
    #pragma unroll
    for (int a = 0; a < 2; a++)
        #pragma unroll
        for (int b = 0; b < 4; b++)
            #pragma unroll
            for (int r = 0; r < 4; r++) acc[a][b][r] = 0.f;

    // 512 threads cover a full 128x32 bf16 tile (8KB) in ONE gload each
    const __hip_bfloat16* Ag = A + (size_t)(row0 + (tid >> 2)) * K + (tid & 3) * 8;
    const __hip_bfloat16* Bg = BT + (size_t)(col0 + (tid >> 2)) * K + (tid & 3) * 8;
    char* AsB = (char*)As;   // 3 buffers x 8 KB
    char* BsB = (char*)Bs;   // 3 buffers x 8 KB

#define G0STAGE(kt, buf) do { \
    __builtin_amdgcn_global_load_lds((glb_char*)(Ag + (kt) * 32), (lds_char*)(AsB + (buf) * 8192 + tid * 16), 16, 0, 0); \
    __builtin_amdgcn_global_load_lds((glb_char*)(Bg + (kt) * 32), (lds_char*)(BsB + (buf) * 8192 + tid * 16), 16, 0, 0); \
} while (0)

    // prologue: two K-steps in flight
    G0STAGE(0, 0);
    G0STAGE(1, 1);

    #pragma unroll
    for (int kt = 0; kt < 16; ++kt) {
        if (kt < 15) asm volatile("s_waitcnt vmcnt(2)" ::: "memory");
        else         asm volatile("s_waitcnt vmcnt(0)" ::: "memory");
        __builtin_amdgcn_s_barrier();
        if (kt < 14) G0STAGE(kt + 2, (kt + 2) % 3);
        const __hip_bfloat16* Asc = As + (kt % 3) * 4096;
        const __hip_bfloat16* Bsc = Bs + (kt % 3) * 4096;
        bf16x8 af[2], bfr[4];
        #pragma unroll
        for (int t = 0; t < 2; t++)
            af[t] = *(const bf16x8*)&Asc[(wi * 32 + t * 16 + l16) * 32 + quad * 8];
        #pragma unroll
        for (int t = 0; t < 4; t++)
            bfr[t] = *(const bf16x8*)&Bsc[(wj * 64 + t * 16 + l16) * 32 + quad * 8];
        #pragma unroll
        for (int ti = 0; ti < 2; ti++)
            #pragma unroll
            for (int tj = 0; tj < 4; tj++) {
                if constexpr (QKPATH)
                    acc[ti][tj] = __builtin_amdgcn_mfma_f32_16x16x32_bf16(bfr[tj], af[ti], acc[ti][tj], 0, 0, 0);
                else
                    acc[ti][tj] = __builtin_amdgcn_mfma_f32_16x16x32_bf16(af[ti], bfr[tj], acc[ti][tj], 0, 0, 0);
            }
    }
#undef G0STAGE

    if constexpr (QKPATH) {
        // swapped: lane holds D[col = quad*4+r][row = l16] -> 4 consecutive d
        int g = row0 >> 7;                               // block-uniform
        int ibase = wi * 32 + l16;                       // local row in graph
        int cb0 = col0 + wj * 64 + quad * 4;
        bool isQ = (col0 < 512);                         // block-uniform
        const float* bias = isQ ? bq : bk;
        int boff = isQ ? 0 : 512;
        __hip_bfloat16* dstbuf = isQ ? qbuf : kbuf;
        #pragma unroll
        for (int tj = 0; tj < 4; tj++) {
            int cb = cb0 + tj * 16;
            float4 bb = *(const float4*)(bias + cb - boff);
            int c = cb - boff;                           // 0..511
            int hh = c >> 6, d = c & 63;
            __hip_bfloat16* dst = dstbuf + ((size_t)(g * 8 + hh) * 128) * 64 + d;
            #pragma unroll
            for (int ti = 0; ti < 2; ti++) {
                int i = ibase + ti * 16;
                bf16x4 v;
                v[0] = f2bf(acc[ti][tj][0] + bb.x);
                v[1] = f2bf(acc[ti][tj][1] + bb.y);
                v[2] = f2bf(acc[ti][tj][2] + bb.z);
                v[3] = f2bf(acc[ti][tj][3] + bb.w);
                *(bf16x4*)(dst + (size_t)i * 64) = v;
            }
        }
    } else {
        // unswapped: lane holds rows quad*4+r (consecutive i in vt), col = l16
        int g = row0 >> 7;
        int i0 = wi * 32 + quad * 4;
        #pragma unroll
        for (int tj = 0; tj < 4; tj++) {
            int c = col0 - 1024 + wj * 64 + tj * 16 + l16;   // 0..511
            int hh = c >> 6, d = c & 63;
            float bvv = bv[c];
            __hip_bfloat16* vdst = vt + ((size_t)(g * 8 + hh) * 64 + d) * 128 + i0;
            #pragma unroll
            for (int ti = 0; ti < 2; ti++) {
                bf16x4 v;
                v[0] = f2bf(acc[ti][tj][0] + bvv);
                v[1] = f2bf(acc[ti][tj][1] + bvv);
                v[2] = f2bf(acc[ti][tj][2] + bvv);
                v[3] = f2bf(acc[ti][tj][3] + bvv);
                *(bf16x4*)(vdst + ti * 16) = v;
            }
        }
    }
}

// ---------------------------------------------------------------------------
// Edge MLP body, 512 threads (8 waves x 64 edges = 512 edges/block).
// Layer-1 bias enters as MFMA C-init. biasE [h][e].
// ---------------------------------------------------------------------------
__device__ __forceinline__ void edge_body(
    int eblk,
    const float* __restrict__ ea,
    const __hip_bfloat16* __restrict__ w1fragt, const float* __restrict__ b1f,
    const __hip_bfloat16* __restrict__ w2at, const float* __restrict__ b2f,
    float* __restrict__ biasE)
{
    int tid = threadIdx.x, wave = tid >> 6, lane = tid & 63;
    int quad = lane >> 4, l16 = lane & 15;
    int eb = eblk * 512 + wave * 64;     // wave owns 64 edges (4 x 16)

    s16x4 eaf[4] = {};
    if (quad == 0) {
        #pragma unroll
        for (int gg = 0; gg < 4; ++gg) {
            float4 e4 = *(const float4*)(ea + (size_t)(eb + gg * 16 + l16) * 4);
            eaf[gg][0] = (short)f2u16(e4.x); eaf[gg][1] = (short)f2u16(e4.y);
            eaf[gg][2] = (short)f2u16(e4.z); eaf[gg][3] = (short)f2u16(e4.w);
        }
    }

    f32x4 c2[4];
    #pragma unroll
    for (int gg = 0; gg < 4; ++gg)
        #pragma unroll
        for (int r = 0; r < 4; ++r) c2[gg][r] = 0.f;

    #pragma unroll 4
    for (int t = 0; t < 32; ++t) {
        s16x4 a1 = *(const s16x4*)(w1fragt + ((size_t)t * 16 + l16) * 4);
        float4 b14 = *(const float4*)(b1f + t * 16 + quad * 4);
        s16x4 a2 = *(const s16x4*)(w2at + ((size_t)t * 64 + lane) * 4);
        #pragma unroll
        for (int gg = 0; gg < 4; ++gg) {
            f32x4 c1;
            c1[0] = b14.x; c1[1] = b14.y; c1[2] = b14.z; c1[3] = b14.w;
            c1 = __builtin_amdgcn_mfma_f32_16x16x16bf16_1k(a1, eaf[gg], c1, 0, 0, 0);
            s16x4 hfrag;
            hfrag[0] = (short)f2u16(fmaxf(c1[0], 0.f));
            hfrag[1] = (short)f2u16(fmaxf(c1[1], 0.f));
            hfrag[2] = (short)f2u16(fmaxf(c1[2], 0.f));
            hfrag[3] = (short)f2u16(fmaxf(c1[3], 0.f));
            c2[gg] = __builtin_amdgcn_mfma_f32_16x16x16bf16_1k(a2, hfrag, c2[gg], 0, 0, 0);
        }
    }
    // c2 lane mapping: head = quad*4+r (quads 0-1), edge = l16.
    if (quad < 2) {
        #pragma unroll
        for (int gg = 0; gg < 4; ++gg) {
            #pragma unroll
            for (int r = 0; r < 4; ++r) {
                int hh = quad * 4 + r;
                biasE[(size_t)hh * E_TOTAL + eb + gg * 16 + l16] = c2[gg][r] + b2f[hh];
            }
        }
    }
}

// ---------------------------------------------------------------------------
// Mega dispatch: 1280 blocks x 512 threads = 5 x 256, GEMM (3/5) and edge
// (2/5) INTERLEAVED (proven mechanism: heterogeneous co-residency fills
// GEMM stall slots; mega is latency-bound).
// ---------------------------------------------------------------------------
__global__ __launch_bounds__(512) void mega_kernel(
    const __hip_bfloat16* __restrict__ A, const __hip_bfloat16* __restrict__ BT,
    const float* __restrict__ bq, const float* __restrict__ bk,
    const float* __restrict__ bv,
    __hip_bfloat16* __restrict__ qbuf, __hip_bfloat16* __restrict__ kbuf,
    __hip_bfloat16* __restrict__ vt,
    const float* __restrict__ ea,
    const __hip_bfloat16* __restrict__ w1fragt, const float* __restrict__ b1f,
    const __hip_bfloat16* __restrict__ w2at, const float* __restrict__ b2f,
    float* __restrict__ biasE)
{
    __shared__ __align__(16) __hip_bfloat16 As[3 * 128 * 32];   // 24 KB (3-buf)
    __shared__ __align__(16) __hip_bfloat16 Bs[3 * 128 * 32];   // 24 KB (3-buf)
    int blk = blockIdx.x;
    int u = blk / 5, v = blk % 5;
    if (v < 3) {
        int tile = u * 3 + v;                 // 0..767
        int row0 = (tile & 63) * 128, col0 = (tile >> 6) * 128;
        if (col0 < 1024)
            gemm0_body<true>(A, BT, row0, col0, bq, bk, bv, qbuf, kbuf, vt, As, Bs);
        else
            gemm0_body<false>(A, BT, row0, col0, bq, bk, bv, qbuf, kbuf, vt, As, Bs);
    } else {
        edge_body(u * 2 + (v - 3), ea, w1fragt, b1f, w2at, b2f, biasE);
    }
}

// ---------------------------------------------------------------------------
// Out-proj GEMM: 128x64 tiles, counted-vmcnt pipeline, swapped operands ->
// lane holds 4 consecutive output columns -> f32x4 stores. (unchanged)
// ---------------------------------------------------------------------------
__global__ __launch_bounds__(256) void gemm1_kernel(
    const __hip_bfloat16* __restrict__ A, const __hip_bfloat16* __restrict__ BT,
    const float* __restrict__ bo, float* __restrict__ out)
{
    const int K = 512;
    __shared__ __align__(16) __hip_bfloat16 As[3 * 128 * 32];   // 24 KB
    __shared__ __align__(16) __hip_bfloat16 Bs[3 * 64 * 32];    // 12 KB
    int tid = threadIdx.x;
    int lane = tid & 63, quad = lane >> 4, l16 = lane & 15;
    int wave = tid >> 6, wi = wave >> 1, wj = wave & 1;
    int row0 = blockIdx.x * 128, col0 = blockIdx.y * 64;

    f32x4 acc[4][2];
    #pragma unroll
    for (int a = 0; a < 4; a++)
        #pragma unroll
        for (int b = 0; b < 2; b++)
            #pragma unroll
            for (int r = 0; r < 4; r++) acc[a][b][r] = 0.f;

    const __hip_bfloat16* Ag0 = A + (size_t)(row0 + (tid >> 2)) * K + (tid & 3) * 8;
    const __hip_bfloat16* Ag1 = Ag0 + (size_t)64 * K;
    const __hip_bfloat16* Bg  = BT + (size_t)(col0 + (tid >> 2)) * K + (tid & 3) * 8;
    char* AsB = (char*)As;
    char* BsB = (char*)Bs;

#define G1STAGE(kt, buf) do { \
    __builtin_amdgcn_global_load_lds((glb_char*)(Ag0 + (kt) * 32), (lds_char*)(AsB + (buf) * 8192 + tid * 16), 16, 0, 0); \
    __builtin_amdgcn_global_load_lds((glb_char*)(Ag1 + (kt) * 32), (lds_char*)(AsB + (buf) * 8192 + 4096 + tid * 16), 16, 0, 0); \
    __builtin_amdgcn_global_load_lds((glb_char*)(Bg + (kt) * 32),  (lds_char*)(BsB + (buf) * 4096 + tid * 16), 16, 0, 0); \
} while (0)

    G1STAGE(0, 0);
    G1STAGE(1, 1);

    #pragma unroll
    for (int kt = 0; kt < 16; ++kt) {
        if (kt < 15) asm volatile("s_waitcnt vmcnt(3)" ::: "memory");
        else         asm volatile("s_waitcnt vmcnt(0)" ::: "memory");
        __builtin_amdgcn_s_barrier();
        if (kt < 14) G1STAGE(kt + 2, (kt + 2) % 3);
        const __hip_bfloat16* Asc = As + (kt % 3) * 4096;
        const __hip_bfloat16* Bsc = Bs + (kt % 3) * 2048;
        bf16x8 af[4], bfr[2];
        #pragma unroll
        for (int t = 0; t < 4; t++)
            af[t] = *(const bf16x8*)&Asc[(wi * 64 + t * 16 + l16) * 32 + quad * 8];
        #pragma unroll
        for (int t = 0; t < 2; t++)
            bfr[t] = *(const bf16x8*)&Bsc[(wj * 32 + t * 16 + l16) * 32 + quad * 8];
        #pragma unroll
        for (int ti = 0; ti < 4; ti++)
            #pragma unroll
            for (int tj = 0; tj < 2; tj++)
                acc[ti][tj] = __builtin_amdgcn_mfma_f32_16x16x32_bf16(bfr[tj], af[ti], acc[ti][tj], 0, 0, 0);
    }
#undef G1STAGE

    // lane holds 4 consecutive columns (quad*4+r) at row l16
    int rbase = row0 + wi * 64 + l16;
    int cb0 = col0 + wj * 32 + quad * 4;
    #pragma unroll
    for (int tj = 0; tj < 2; tj++) {
        int cb = cb0 + tj * 16;
        float4 bb = *(const float4*)(bo + cb);
        #pragma unroll
        for (int ti = 0; ti < 4; ti++) {
            int row = rbase + ti * 16;
            f32x4 v;
            v[0] = acc[ti][tj][0] + bb.x;
            v[1] = acc[ti][tj][1] + bb.y;
            v[2] = acc[ti][tj][2] + bb.z;
            v[3] = acc[ti][tj][3] + bb.w;
            *(f32x4*)(out + (size_t)row * 512 + cb) = v;
        }
    }
}

// ---------------------------------------------------------------------------
// Attention: one workgroup per (graph, head), 512 threads (8 waves, one
// 16-row i-tile each). Q/K per-(g,h)-contiguous (dense 2KB wave reads).
// Swapped operands: S written f32x4, O written bf16x4. V-frags for PV first
// half prefetched pre-scatter (T14). (unchanged)
// ---------------------------------------------------------------------------
#define SS 132
__global__ __launch_bounds__(512) void attn_kernel(
    const __hip_bfloat16* __restrict__ qbuf,
    const __hip_bfloat16* __restrict__ kbuf,
    const __hip_bfloat16* __restrict__ vt,
    const float* __restrict__ biasE,
    const int* __restrict__ eidx,
    __hip_bfloat16* __restrict__ O)
{
    __shared__ __align__(16) float S[128 * SS];   // 67584 B
    int blk = blockIdx.x, g = blk & 63, h = blk >> 6;
    int tid = threadIdx.x, wave = tid >> 6, lane = tid & 63;
    int quad = lane >> 4, l16 = lane & 15;

    // ---- prefetch scatter operands (independent of QK^T) into registers
    int   sa[8];   // packed LDS address ls*SS+ld
    float bvv[8];
    #pragma unroll
    for (int u = 0; u < 8; ++u) {
        int idx = g * 4096 + tid + u * 512;
        int ls = eidx[idx] & 127;
        int ld = eidx[E_TOTAL + idx] & 127;
        sa[u] = ls * SS + ld;
        bvv[u] = biasE[(size_t)h * E_TOTAL + idx];   // coalesced [h][e]
    }

    const __hip_bfloat16* qbase = qbuf + (size_t)(g * 8 + h) * 128 * 64;
    const __hip_bfloat16* kbase = kbuf + (size_t)(g * 8 + h) * 128 * 64;
    const __hip_bfloat16* vbase = vt + (size_t)(g * 8 + h) * 64 * 128;

    // ---- QK^T (swapped): D[j = tj*16+quad*4+r][i = wave*16+l16]
    f32x4 acc[8];
    #pragma unroll
    for (int j = 0; j < 8; j++)
        #pragma unroll
        for (int r = 0; r < 4; r++) acc[j][r] = 0.f;

    #pragma unroll
    for (int k0 = 0; k0 < 64; k0 += 32) {
        int m = wave * 16 + l16;
        bf16x8 af = *(const bf16x8*)(qbase + (size_t)m * 64 + k0 + quad * 8);
        #pragma unroll
        for (int tj = 0; tj < 8; tj++) {
            int n = tj * 16 + l16;
            bf16x8 bfr = *(const bf16x8*)(kbase + (size_t)n * 64 + k0 + quad * 8);
            acc[tj] = __builtin_amdgcn_mfma_f32_16x16x32_bf16(bfr, af, acc[tj], 0, 0, 0);
        }
    }
    {
        int i = wave * 16 + l16;
        #pragma unroll
        for (int tj = 0; tj < 8; tj++) {
            f32x4 sv;
            sv[0] = acc[tj][0] * 0.125f;
            sv[1] = acc[tj][1] * 0.125f;
            sv[2] = acc[tj][2] * 0.125f;
            sv[3] = acc[tj][3] * 0.125f;
            *(f32x4*)&S[i * SS + tj * 16 + quad * 4] = sv;
        }
    }

    // ---- prefetch V frags for PV first half (k0 = 0, 32) into registers
    bf16x8 vpre[8];
    #pragma unroll
    for (int kh = 0; kh < 2; kh++)
        #pragma unroll
        for (int tj = 0; tj < 4; tj++)
            vpre[kh * 4 + tj] = *(const bf16x8*)(vbase + (size_t)(tj * 16 + l16) * 128 + kh * 32 + quad * 8);

    __syncthreads();

    // ---- edge bias scatter from registers (duplicates accumulate)
    #pragma unroll
    for (int u = 0; u < 8; ++u)
        atomicAdd(&S[sa[u]], bvv[u]);
    __syncthreads();

    // ---- softmax over j; wave handles 16 rows
    #pragma unroll 4
    for (int r = wave * 16; r < wave * 16 + 16; ++r) {
        float2 v = *(const float2*)&S[r * SS + 2 * lane];
        float m = fmaxf(v.x, v.y);
        #pragma unroll
        for (int off = 32; off > 0; off >>= 1) m = fmaxf(m, __shfl_xor(m, off));
        float e0 = __expf(v.x - m), e1 = __expf(v.y - m);
        float s = e0 + e1;
        #pragma unroll
        for (int off = 32; off > 0; off >>= 1) s += __shfl_xor(s, off);
        float inv = 1.0f / s;
        float2 o; o.x = e0 * inv; o.y = e1 * inv;
        *(float2*)&S[r * SS + 2 * lane] = o;
    }
    __syncthreads();

    // ---- PV (swapped): D[d = tj*16+quad*4+r][i = wave*16+l16]
    f32x4 oacc[4];
    #pragma unroll
    for (int j = 0; j < 4; j++)
        #pragma unroll
        for (int r = 0; r < 4; r++) oacc[j][r] = 0.f;

    #pragma unroll
    for (int k0 = 0; k0 < 128; k0 += 32) {
        int m = wave * 16 + l16;
        const float* p = &S[m * SS + k0 + quad * 8];
        f32x4 xa = *(const f32x4*)p;
        f32x4 xb = *(const f32x4*)(p + 4);
        bf16x8 af;
        af[0] = f2bf(xa[0]); af[1] = f2bf(xa[1]); af[2] = f2bf(xa[2]); af[3] = f2bf(xa[3]);
        af[4] = f2bf(xb[0]); af[5] = f2bf(xb[1]); af[6] = f2bf(xb[2]); af[7] = f2bf(xb[3]);
        #pragma unroll
        for (int tj = 0; tj < 4; tj++) {
            bf16x8 bfr = (k0 < 64)
                ? vpre[(k0 >> 5) * 4 + tj]
                : *(const bf16x8*)(vbase + (size_t)(tj * 16 + l16) * 128 + k0 + quad * 8);
            oacc[tj] = __builtin_amdgcn_mfma_f32_16x16x32_bf16(bfr, af, oacc[tj], 0, 0, 0);
        }
    }
    {
        int i = wave * 16 + l16;
        __hip_bfloat16* obase = O + (size_t)(g * 128 + i) * 512 + h * 64 + quad * 4;
        #pragma unroll
        for (int tj = 0; tj < 4; tj++) {
            bf16x4 ov;
            ov[0] = f2bf(oacc[tj][0]);
            ov[1] = f2bf(oacc[tj][1]);
            ov[2] = f2bf(oacc[tj][2]);
            ov[3] = f2bf(oacc[tj][3]);
            *(bf16x4*)(obase + tj * 16) = ov;
        }
    }
}

// ---------------------------------------------------------------------------
// Workspace layout (bytes), packed tight (44.6 MB).
// xbf (pre-cast x) ALIASES O: live ranges [prep->mega] vs [attn->gemm1].
// ---------------------------------------------------------------------------
#define WS_WQKVT 0x0          // 1536*512 bf16 = 1.5 MB
#define WS_WOT   0x180000     // 512*512 bf16 = 0.5 MB -> ends 0x200000
#define WS_W1FR  0x200000     // 4 KB
#define WS_B1F   0x202000     // 2 KB
#define WS_W2AT  0x202800     // 16 KB -> 0x206800
#define WS_B2F   0x206800     // 32 B
#define WS_Q     0x210000     // 8 MB ([g*8+h][i][64]) -> 0xA10000
#define WS_K     0xA10000     // 8 MB ([g*8+h][j][64]) -> 0x1210000
#define WS_VT    0x1210000    // 8 MB ([g*8+h][d][128]) -> 0x1A10000
#define WS_BIASE 0x1A10000    // 8 MB ([h][e] fp32) -> 0x2210000
#define WS_O     0x2210000    // 8 MB -> 0x2A10000 (aliased by xbf)
#define WS_XBF   WS_O

extern "C" void kernel_launch(void* const* d_in, const int* in_sizes, int n_in,
                              void* d_out, int out_size, void* d_ws, size_t ws_size,
                              hipStream_t stream) {
    const float* x    = (const float*)d_in[0];
    const int*   eidx = (const int*)d_in[1];
    const float* ea   = (const float*)d_in[2];
    // d_in[3] = batch, d_in[4] = n_g (unused; block structure is fixed)
    const float* Wq = (const float*)d_in[5];
    const float* bq = (const float*)d_in[6];
    const float* Wk = (const float*)d_in[7];
    const float* bk = (const float*)d_in[8];
    const float* Wv = (const float*)d_in[9];
    const float* bv = (const float*)d_in[10];
    const float* Wo = (const float*)d_in[11];
    const float* bo = (const float*)d_in[12];
    const float* W1 = (const float*)d_in[13];
    const float* b1 = (const float*)d_in[14];
    const float* W2 = (const float*)d_in[15];
    const float* b2 = (const float*)d_in[16];

    char* ws = (char*)d_ws;
    __hip_bfloat16* wqkvt   = (__hip_bfloat16*)(ws + WS_WQKVT);
    __hip_bfloat16* wot     = (__hip_bfloat16*)(ws + WS_WOT);
    __hip_bfloat16* w1fragt = (__hip_bfloat16*)(ws + WS_W1FR);
    float* b1f   = (float*)(ws + WS_B1F);
    __hip_bfloat16* w2at    = (__hip_bfloat16*)(ws + WS_W2AT);
    float* b2f   = (float*)(ws + WS_B2F);
    __hip_bfloat16* qbuf = (__hip_bfloat16*)(ws + WS_Q);
    __hip_bfloat16* kbuf = (__hip_bfloat16*)(ws + WS_K);
    __hip_bfloat16* vt  = (__hip_bfloat16*)(ws + WS_VT);
    float* biasE = (float*)(ws + WS_BIASE);
    __hip_bfloat16* O   = (__hip_bfloat16*)(ws + WS_O);
    __hip_bfloat16* xbf = (__hip_bfloat16*)(ws + WS_XBF);

    prep_kernel<<<257 + 2048, 256, 0, stream>>>(Wq, Wk, Wv, Wo, W1, b1, W2, b2,
                                                x, xbf,
                                                wqkvt, wot, w1fragt, b1f, w2at, b2f);
    mega_kernel<<<1280, 512, 0, stream>>>(
        xbf, wqkvt, bq, bk, bv, qbuf, kbuf, vt,
        ea, w1fragt, b1f, w2at, b2f, biasE);
    attn_kernel<<<GRAPHS * NHEADS, 512, 0, stream>>>(qbuf, kbuf, vt, biasE, eidx, O);
    gemm1_kernel<<<dim3(NNODES / 128, 512 / 64), 256, 0, stream>>>(
        O, wot, bo, (float*)d_out);
}

// Round 10
// 195.777 us; speedup vs baseline: 1.0218x; 1.0218x over previous
//
#include <hip/hip_runtime.h>
#include <hip/hip_bf16.h>

// Problem constants (fixed by setup_inputs)
#define E_TOTAL 262144
#define NG      128
#define GRAPHS  64
#define NHEADS  8
#define DKH     64
#define DMODEL  512
#define NNODES  8192

typedef __bf16 bf16x8 __attribute__((ext_vector_type(8)));
typedef __bf16 bf16x4 __attribute__((ext_vector_type(4)));
typedef float  f32x4  __attribute__((ext_vector_type(4)));
typedef short  s16x4  __attribute__((ext_vector_type(4)));

typedef __attribute__((address_space(3))) char lds_char;
typedef const __attribute__((address_space(1))) char glb_char;

__device__ inline __hip_bfloat16 f2hbf(float f) { return __float2bfloat16(f); }
__device__ inline unsigned short f2u16(float f) {
    return __builtin_bit_cast(unsigned short, __float2bfloat16(f));
}
__device__ inline __bf16 f2bf(float f) {
    return __builtin_bit_cast(__bf16, f2u16(f));
}
__device__ inline bf16x8 cvt8(float4 lo, float4 hi) {
    bf16x8 o;
    o[0] = f2bf(lo.x); o[1] = f2bf(lo.y); o[2] = f2bf(lo.z); o[3] = f2bf(lo.w);
    o[4] = f2bf(hi.x); o[5] = f2bf(hi.y); o[6] = f2bf(hi.z); o[7] = f2bf(hi.w);
    return o;
}

// ---------------------------------------------------------------------------
// Prep: weight transpose/cast + edge-MLP frag tables + x fp32->bf16 pre-pass.
// Tables (w1fragt | b1f | w2at) now packed CONTIGUOUS (22.5 KB) so mega's
// edge blocks can LDS-stage them with one int4 copy.
// ---------------------------------------------------------------------------
__global__ __launch_bounds__(256) void prep_kernel(
    const float* __restrict__ Wq, const float* __restrict__ Wk,
    const float* __restrict__ Wv, const float* __restrict__ Wo,
    const float* __restrict__ W1, const float* __restrict__ b1,
    const float* __restrict__ W2, const float* __restrict__ b2,
    const float* __restrict__ x, __hip_bfloat16* __restrict__ xbf,
    __hip_bfloat16* __restrict__ wqkvt, __hip_bfloat16* __restrict__ wot,
    __hip_bfloat16* __restrict__ w1fragt, float* __restrict__ b1f,
    __hip_bfloat16* __restrict__ w2at, float* __restrict__ b2f)
{
    int blk = blockIdx.x, tid = threadIdx.x;
    if (blk < 256) {
        __shared__ __align__(16) __hip_bfloat16 tile[64][65];
        const float* src;
        __hip_bfloat16* dstT;
        int n0, k0, nb;
        if (blk < 192) {
            int nt = blk % 24, ktile = blk / 24;
            n0 = nt * 64; k0 = ktile * 64;
            if (n0 < 512)       { src = Wq; nb = n0; }
            else if (n0 < 1024) { src = Wk; nb = n0 - 512; }
            else                { src = Wv; nb = n0 - 1024; }
            dstT = wqkvt;
        } else {
            int t = blk - 192;
            n0 = (t % 8) * 64; k0 = (t / 8) * 64; nb = n0;
            src = Wo; dstT = wot;
        }
        #pragma unroll
        for (int i = 0; i < 16; ++i) {
            int idx = tid + i * 256;
            int kr = idx >> 6, nc = idx & 63;
            tile[kr][nc] = f2hbf(src[(size_t)(k0 + kr) * 512 + nb + nc]);
        }
        __syncthreads();
        #pragma unroll
        for (int i = 0; i < 16; ++i) {
            int idx = tid + i * 256;
            int nr = idx >> 6, kc = idx & 63;
            dstT[(size_t)(n0 + nr) * 512 + k0 + kc] = tile[kc][nr];
        }
    } else if (blk == 256) {
        __hip_bfloat16 z = f2hbf(0.f);
        // w1fragt: [512][4] (K=16 MFMA A-frag)
        for (int n = tid; n < 512; n += 256) {
            #pragma unroll
            for (int j = 0; j < 4; ++j) w1fragt[n * 4 + j] = f2hbf(W1[(size_t)j * 512 + n]);
        }
        for (int i = tid; i < 512; i += 256) b1f[i] = b1[i];
        // w2at: [32][64][4], W2 is (512,8) row-major
        for (int i = tid; i < 32 * 64 * 4; i += 256) {
            int t = i >> 8, lane = (i >> 2) & 63, j = i & 3;
            int q = lane >> 4, l = lane & 15;
            w2at[i] = (l < 8) ? f2hbf(W2[(size_t)(16 * t + 4 * q + j) * 8 + l]) : z;
        }
        if (tid < 8) b2f[tid] = b2[tid];
    } else {
        // x -> bf16, 2048 elems per block (8 per thread)
        int base = (blk - 257) * 2048 + tid * 8;
        float4 lo = *(const float4*)(x + base);
        float4 hi = *(const float4*)(x + base + 4);
        *(bf16x8*)(xbf + base) = cvt8(lo, hi);
    }
}

// ---------------------------------------------------------------------------
// QKV GEMM body, 128x128 tile, 512 threads (8 waves, 4x2 grid, 32x64
// sub-tile/wave), triple-buffered counted-vmcnt pipeline (R9 state).
// ---------------------------------------------------------------------------
template <bool QKPATH>
__device__ __forceinline__ void gemm0_body(
    const __hip_bfloat16* __restrict__ A, const __hip_bfloat16* __restrict__ BT,
    int row0, int col0,
    const float* __restrict__ bq, const float* __restrict__ bk,
    const float* __restrict__ bv,
    __hip_bfloat16* __restrict__ qbuf, __hip_bfloat16* __restrict__ kbuf,
    __hip_bfloat16* __restrict__ vt,
    __hip_bfloat16* __restrict__ As, __hip_bfloat16* __restrict__ Bs)
{
    const int K = 512;
    int tid = threadIdx.x;                 // 0..511
    int lane = tid & 63, quad = lane >> 4, l16 = lane & 15;
    int wave = tid >> 6;                   // 0..7
    int wi = wave >> 1, wj = wave & 1;     // 4 x 2 wave grid

    f32x4 acc[2][4];
    #pragma unroll
    for (int a = 0; a < 2; a++)
        #pragma unroll
        for (int b = 0; b < 4; b++)
            #pragma unroll
            for (int r = 0; r < 4; r++) acc[a][b][r] = 0.f;

    // 512 threads cover a full 128x32 bf16 tile (8KB) in ONE gload each
    const __hip_bfloat16* Ag = A + (size_t)(row0 + (tid >> 2)) * K + (tid & 3) * 8;
    const __hip_bfloat16* Bg = BT + (size_t)(col0 + (tid >> 2)) * K + (tid & 3) * 8;
    char* AsB = (char*)As;   // 3 buffers x 8 KB
    char* BsB = (char*)Bs;   // 3 buffers x 8 KB

#define G0STAGE(kt, buf) do { \
    __builtin_amdgcn_global_load_lds((glb_char*)(Ag + (kt) * 32), (lds_char*)(AsB + (buf) * 8192 + tid * 16), 16, 0, 0); \
    __builtin_amdgcn_global_load_lds((glb_char*)(Bg + (kt) * 32), (lds_char*)(BsB + (buf) * 8192 + tid * 16), 16, 0, 0); \
} while (0)

    // prologue: two K-steps in flight
    G0STAGE(0, 0);
    G0STAGE(1, 1);

    #pragma unroll
    for (int kt = 0; kt < 16; ++kt) {
        if (kt < 15) asm volatile("s_waitcnt vmcnt(2)" ::: "memory");
        else         asm volatile("s_waitcnt vmcnt(0)" ::: "memory");
        __builtin_amdgcn_s_barrier();
        if (kt < 14) G0STAGE(kt + 2, (kt + 2) % 3);
        const __hip_bfloat16* Asc = As + (kt % 3) * 4096;
        const __hip_bfloat16* Bsc = Bs + (kt % 3) * 4096;
        bf16x8 af[2], bfr[4];
        #pragma unroll
        for (int t = 0; t < 2; t++)
            af[t] = *(const bf16x8*)&Asc[(wi * 32 + t * 16 + l16) * 32 + quad * 8];
        #pragma unroll
        for (int t = 0; t < 4; t++)
            bfr[t] = *(const bf16x8*)&Bsc[(wj * 64 + t * 16 + l16) * 32 + quad * 8];
        #pragma unroll
        for (int ti = 0; ti < 2; ti++)
            #pragma unroll
            for (int tj = 0; tj < 4; tj++) {
                if constexpr (QKPATH)
                    acc[ti][tj] = __builtin_amdgcn_mfma_f32_16x16x32_bf16(bfr[tj], af[ti], acc[ti][tj], 0, 0, 0);
                else
                    acc[ti][tj] = __builtin_amdgcn_mfma_f32_16x16x32_bf16(af[ti], bfr[tj], acc[ti][tj], 0, 0, 0);
            }
    }
#undef G0STAGE

    if constexpr (QKPATH) {
        // swapped: lane holds D[col = quad*4+r][row = l16] -> 4 consecutive d
        int g = row0 >> 7;                               // block-uniform
        int ibase = wi * 32 + l16;                       // local row in graph
        int cb0 = col0 + wj * 64 + quad * 4;
        bool isQ = (col0 < 512);                         // block-uniform
        const float* bias = isQ ? bq : bk;
        int boff = isQ ? 0 : 512;
        __hip_bfloat16* dstbuf = isQ ? qbuf : kbuf;
        #pragma unroll
        for (int tj = 0; tj < 4; tj++) {
            int cb = cb0 + tj * 16;
            float4 bb = *(const float4*)(bias + cb - boff);
            int c = cb - boff;                           // 0..511
            int hh = c >> 6, d = c & 63;
            __hip_bfloat16* dst = dstbuf + ((size_t)(g * 8 + hh) * 128) * 64 + d;
            #pragma unroll
            for (int ti = 0; ti < 2; ti++) {
                int i = ibase + ti * 16;
                bf16x4 v;
                v[0] = f2bf(acc[ti][tj][0] + bb.x);
                v[1] = f2bf(acc[ti][tj][1] + bb.y);
                v[2] = f2bf(acc[ti][tj][2] + bb.z);
                v[3] = f2bf(acc[ti][tj][3] + bb.w);
                *(bf16x4*)(dst + (size_t)i * 64) = v;
            }
        }
    } else {
        // unswapped: lane holds rows quad*4+r (consecutive i in vt), col = l16
        int g = row0 >> 7;
        int i0 = wi * 32 + quad * 4;
        #pragma unroll
        for (int tj = 0; tj < 4; tj++) {
            int c = col0 - 1024 + wj * 64 + tj * 16 + l16;   // 0..511
            int hh = c >> 6, d = c & 63;
            float bvv = bv[c];
            __hip_bfloat16* vdst = vt + ((size_t)(g * 8 + hh) * 64 + d) * 128 + i0;
            #pragma unroll
            for (int ti = 0; ti < 2; ti++) {
                bf16x4 v;
                v[0] = f2bf(acc[ti][tj][0] + bvv);
                v[1] = f2bf(acc[ti][tj][1] + bvv);
                v[2] = f2bf(acc[ti][tj][2] + bvv);
                v[3] = f2bf(acc[ti][tj][3] + bvv);
                *(bf16x4*)(vdst + ti * 16) = v;
            }
        }
    }
}

// ---------------------------------------------------------------------------
// Edge MLP body, 512 threads (8 waves x 64 edges). Tables (22.5 KB) are
// LDS-STAGED by the caller (edge blocks reuse the GEMM As/Bs LDS they don't
// otherwise touch): the t-loop's 96 small global loads per wave become
// ds_reads (~120cy, conflict-free: a1/b14 broadcast, a2 2-way-free).
// Layer-1 bias enters as MFMA C-init.
// ---------------------------------------------------------------------------
__device__ __forceinline__ void edge_body(
    int eblk,
    const float* __restrict__ ea,
    const __hip_bfloat16* w1s, const float* b1s, const __hip_bfloat16* w2s,
    const float* __restrict__ b2f,
    float* __restrict__ biasE)
{
    int tid = threadIdx.x, wave = tid >> 6, lane = tid & 63;
    int quad = lane >> 4, l16 = lane & 15;
    int eb = eblk * 512 + wave * 64;     // wave owns 64 edges (4 x 16)

    s16x4 eaf[4] = {};
    if (quad == 0) {
        #pragma unroll
        for (int gg = 0; gg < 4; ++gg) {
            float4 e4 = *(const float4*)(ea + (size_t)(eb + gg * 16 + l16) * 4);
            eaf[gg][0] = (short)f2u16(e4.x); eaf[gg][1] = (short)f2u16(e4.y);
            eaf[gg][2] = (short)f2u16(e4.z); eaf[gg][3] = (short)f2u16(e4.w);
        }
    }

    f32x4 c2[4];
    #pragma unroll
    for (int gg = 0; gg < 4; ++gg)
        #pragma unroll
        for (int r = 0; r < 4; ++r) c2[gg][r] = 0.f;

    #pragma unroll 4
    for (int t = 0; t < 32; ++t) {
        s16x4 a1 = *(const s16x4*)(w1s + ((size_t)t * 16 + l16) * 4);
        float4 b14 = *(const float4*)(b1s + t * 16 + quad * 4);
        s16x4 a2 = *(const s16x4*)(w2s + ((size_t)t * 64 + lane) * 4);
        #pragma unroll
        for (int gg = 0; gg < 4; ++gg) {
            f32x4 c1;
            c1[0] = b14.x; c1[1] = b14.y; c1[2] = b14.z; c1[3] = b14.w;
            c1 = __builtin_amdgcn_mfma_f32_16x16x16bf16_1k(a1, eaf[gg], c1, 0, 0, 0);
            s16x4 hfrag;
            hfrag[0] = (short)f2u16(fmaxf(c1[0], 0.f));
            hfrag[1] = (short)f2u16(fmaxf(c1[1], 0.f));
            hfrag[2] = (short)f2u16(fmaxf(c1[2], 0.f));
            hfrag[3] = (short)f2u16(fmaxf(c1[3], 0.f));
            c2[gg] = __builtin_amdgcn_mfma_f32_16x16x16bf16_1k(a2, hfrag, c2[gg], 0, 0, 0);
        }
    }
    // c2 lane mapping: head = quad*4+r (quads 0-1), edge = l16.
    if (quad < 2) {
        #pragma unroll
        for (int gg = 0; gg < 4; ++gg) {
            #pragma unroll
            for (int r = 0; r < 4; ++r) {
                int hh = quad * 4 + r;
                biasE[(size_t)hh * E_TOTAL + eb + gg * 16 + l16] = c2[gg][r] + b2f[hh];
            }
        }
    }
}

// ---------------------------------------------------------------------------
// Mega dispatch: 1280 blocks x 512 threads, GEMM (3/5) / edge (2/5)
// interleaved, with XCD-BIJECTIVE SWIZZLE (1280 = 8*160): each XCD gets 160
// consecutive LOGICAL blocks -> same-B-panel GEMM tiles and their x rows
// are served from the XCD's own L2 (~200cy) instead of L3/cross-XCD.
// Mega is latency-bound on staging loads; this attacks exactly that.
// ---------------------------------------------------------------------------
__global__ __launch_bounds__(512) void mega_kernel(
    const __hip_bfloat16* __restrict__ A, const __hip_bfloat16* __restrict__ BT,
    const float* __restrict__ bq, const float* __restrict__ bk,
    const float* __restrict__ bv,
    __hip_bfloat16* __restrict__ qbuf, __hip_bfloat16* __restrict__ kbuf,
    __hip_bfloat16* __restrict__ vt,
    const float* __restrict__ ea,
    const char* __restrict__ tabg,   // contiguous w1fragt|b1f|w2at (22.5 KB)
    const float* __restrict__ b2f,
    float* __restrict__ biasE)
{
    __shared__ __align__(16) __hip_bfloat16 As[3 * 128 * 32];   // 24 KB (3-buf)
    __shared__ __align__(16) __hip_bfloat16 Bs[3 * 128 * 32];   // 24 KB (3-buf)
    int blk0 = blockIdx.x;
    int blk = (blk0 & 7) * 160 + (blk0 >> 3);   // XCD-bijective swizzle
    int u = blk / 5, v = blk % 5;
    if (v < 3) {
        int tile = u * 3 + v;                 // 0..767
        int row0 = (tile & 63) * 128, col0 = (tile >> 6) * 128;
        if (col0 < 1024)
            gemm0_body<true>(A, BT, row0, col0, bq, bk, bv, qbuf, kbuf, vt, As, Bs);
        else
            gemm0_body<false>(A, BT, row0, col0, bq, bk, bv, qbuf, kbuf, vt, As, Bs);
    } else {
        // stage tables into the (otherwise unused) GEMM LDS: 1408 int4
        int tid = threadIdx.x;
        int4* dst = (int4*)As;
        const int4* srcv = (const int4*)tabg;
        #pragma unroll
        for (int i = 0; i < 3; ++i) {
            int idx = tid + i * 512;
            if (idx < 1408) dst[idx] = srcv[idx];
        }
        __syncthreads();
        const __hip_bfloat16* w1s = (const __hip_bfloat16*)As;
        const float* b1s = (const float*)((const char*)As + 0x1000);
        const __hip_bfloat16* w2s = (const __hip_bfloat16*)((const char*)As + 0x1800);
        edge_body(u * 2 + (v - 3), ea, w1s, b1s, w2s, b2f, biasE);
    }
}

// ---------------------------------------------------------------------------
// Out-proj GEMM: 128x64 tiles, counted-vmcnt pipeline, swapped operands ->
// lane holds 4 consecutive output columns -> f32x4 stores. (unchanged)
// ---------------------------------------------------------------------------
__global__ __launch_bounds__(256) void gemm1_kernel(
    const __hip_bfloat16* __restrict__ A, const __hip_bfloat16* __restrict__ BT,
    const float* __restrict__ bo, float* __restrict__ out)
{
    const int K = 512;
    __shared__ __align__(16) __hip_bfloat16 As[3 * 128 * 32];   // 24 KB
    __shared__ __align__(16) __hip_bfloat16 Bs[3 * 64 * 32];    // 12 KB
    int tid = threadIdx.x;
    int lane = tid & 63, quad = lane >> 4, l16 = lane & 15;
    int wave = tid >> 6, wi = wave >> 1, wj = wave & 1;
    int row0 = blockIdx.x * 128, col0 = blockIdx.y * 64;

    f32x4 acc[4][2];
    #pragma unroll
    for (int a = 0; a < 4; a++)
        #pragma unroll
        for (int b = 0; b < 2; b++)
            #pragma unroll
            for (int r = 0; r < 4; r++) acc[a][b][r] = 0.f;

    const __hip_bfloat16* Ag0 = A + (size_t)(row0 + (tid >> 2)) * K + (tid & 3) * 8;
    const __hip_bfloat16* Ag1 = Ag0 + (size_t)64 * K;
    const __hip_bfloat16* Bg  = BT + (size_t)(col0 + (tid >> 2)) * K + (tid & 3) * 8;
    char* AsB = (char*)As;
    char* BsB = (char*)Bs;

#define G1STAGE(kt, buf) do { \
    __builtin_amdgcn_global_load_lds((glb_char*)(Ag0 + (kt) * 32), (lds_char*)(AsB + (buf) * 8192 + tid * 16), 16, 0, 0); \
    __builtin_amdgcn_global_load_lds((glb_char*)(Ag1 + (kt) * 32), (lds_char*)(AsB + (buf) * 8192 + 4096 + tid * 16), 16, 0, 0); \
    __builtin_amdgcn_global_load_lds((glb_char*)(Bg + (kt) * 32),  (lds_char*)(BsB + (buf) * 4096 + tid * 16), 16, 0, 0); \
} while (0)

    G1STAGE(0, 0);
    G1STAGE(1, 1);

    #pragma unroll
    for (int kt = 0; kt < 16; ++kt) {
        if (kt < 15) asm volatile("s_waitcnt vmcnt(3)" ::: "memory");
        else         asm volatile("s_waitcnt vmcnt(0)" ::: "memory");
        __builtin_amdgcn_s_barrier();
        if (kt < 14) G1STAGE(kt + 2, (kt + 2) % 3);
        const __hip_bfloat16* Asc = As + (kt % 3) * 4096;
        const __hip_bfloat16* Bsc = Bs + (kt % 3) * 2048;
        bf16x8 af[4], bfr[2];
        #pragma unroll
        for (int t = 0; t < 4; t++)
            af[t] = *(const bf16x8*)&Asc[(wi * 64 + t * 16 + l16) * 32 + quad * 8];
        #pragma unroll
        for (int t = 0; t < 2; t++)
            bfr[t] = *(const bf16x8*)&Bsc[(wj * 32 + t * 16 + l16) * 32 + quad * 8];
        #pragma unroll
        for (int ti = 0; ti < 4; ti++)
            #pragma unroll
            for (int tj = 0; tj < 2; tj++)
                acc[ti][tj] = __builtin_amdgcn_mfma_f32_16x16x32_bf16(bfr[tj], af[ti], acc[ti][tj], 0, 0, 0);
    }
#undef G1STAGE

    // lane holds 4 consecutive columns (quad*4+r) at row l16
    int rbase = row0 + wi * 64 + l16;
    int cb0 = col0 + wj * 32 + quad * 4;
    #pragma unroll
    for (int tj = 0; tj < 2; tj++) {
        int cb = cb0 + tj * 16;
        float4 bb = *(const float4*)(bo + cb);
        #pragma unroll
        for (int ti = 0; ti < 4; ti++) {
            int row = rbase + ti * 16;
            f32x4 v;
            v[0] = acc[ti][tj][0] + bb.x;
            v[1] = acc[ti][tj][1] + bb.y;
            v[2] = acc[ti][tj][2] + bb.z;
            v[3] = acc[ti][tj][3] + bb.w;
            *(f32x4*)(out + (size_t)row * 512 + cb) = v;
        }
    }
}

// ---------------------------------------------------------------------------
// Attention: one workgroup per (graph, head), 512 threads (8 waves, one
// 16-row i-tile each). Q/K per-(g,h)-contiguous (dense 2KB wave reads).
// Swapped operands: S written f32x4, O written bf16x4. V-frags for PV first
// half prefetched pre-scatter (T14). (unchanged)
// ---------------------------------------------------------------------------
#define SS 132
__global__ __launch_bounds__(512) void attn_kernel(
    const __hip_bfloat16* __restrict__ qbuf,
    const __hip_bfloat16* __restrict__ kbuf,
    const __hip_bfloat16* __restrict__ vt,
    const float* __restrict__ biasE,
    const int* __restrict__ eidx,
    __hip_bfloat16* __restrict__ O)
{
    __shared__ __align__(16) float S[128 * SS];   // 67584 B
    int blk = blockIdx.x, g = blk & 63, h = blk >> 6;
    int tid = threadIdx.x, wave = tid >> 6, lane = tid & 63;
    int quad = lane >> 4, l16 = lane & 15;

    // ---- prefetch scatter operands (independent of QK^T) into registers
    int   sa[8];   // packed LDS address ls*SS+ld
    float bvv[8];
    #pragma unroll
    for (int u = 0; u < 8; ++u) {
        int idx = g * 4096 + tid + u * 512;
        int ls = eidx[idx] & 127;
        int ld = eidx[E_TOTAL + idx] & 127;
        sa[u] = ls * SS + ld;
        bvv[u] = biasE[(size_t)h * E_TOTAL + idx];   // coalesced [h][e]
    }

    const __hip_bfloat16* qbase = qbuf + (size_t)(g * 8 + h) * 128 * 64;
    const __hip_bfloat16* kbase = kbuf + (size_t)(g * 8 + h) * 128 * 64;
    const __hip_bfloat16* vbase = vt + (size_t)(g * 8 + h) * 64 * 128;

    // ---- QK^T (swapped): D[j = tj*16+quad*4+r][i = wave*16+l16]
    f32x4 acc[8];
    #pragma unroll
    for (int j = 0; j < 8; j++)
        #pragma unroll
        for (int r = 0; r < 4; r++) acc[j][r] = 0.f;

    #pragma unroll
    for (int k0 = 0; k0 < 64; k0 += 32) {
        int m = wave * 16 + l16;
        bf16x8 af = *(const bf16x8*)(qbase + (size_t)m * 64 + k0 + quad * 8);
        #pragma unroll
        for (int tj = 0; tj < 8; tj++) {
            int n = tj * 16 + l16;
            bf16x8 bfr = *(const bf16x8*)(kbase + (size_t)n * 64 + k0 + quad * 8);
            acc[tj] = __builtin_amdgcn_mfma_f32_16x16x32_bf16(bfr, af, acc[tj], 0, 0, 0);
        }
    }
    {
        int i = wave * 16 + l16;
        #pragma unroll
        for (int tj = 0; tj < 8; tj++) {
            f32x4 sv;
            sv[0] = acc[tj][0] * 0.125f;
            sv[1] = acc[tj][1] * 0.125f;
            sv[2] = acc[tj][2] * 0.125f;
            sv[3] = acc[tj][3] * 0.125f;
            *(f32x4*)&S[i * SS + tj * 16 + quad * 4] = sv;
        }
    }

    // ---- prefetch V frags for PV first half (k0 = 0, 32) into registers
    bf16x8 vpre[8];
    #pragma unroll
    for (int kh = 0; kh < 2; kh++)
        #pragma unroll
        for (int tj = 0; tj < 4; tj++)
            vpre[kh * 4 + tj] = *(const bf16x8*)(vbase + (size_t)(tj * 16 + l16) * 128 + kh * 32 + quad * 8);

    __syncthreads();

    // ---- edge bias scatter from registers (duplicates accumulate)
    #pragma unroll
    for (int u = 0; u < 8; ++u)
        atomicAdd(&S[sa[u]], bvv[u]);
    __syncthreads();

    // ---- softmax over j; wave handles 16 rows
    #pragma unroll 4
    for (int r = wave * 16; r < wave * 16 + 16; ++r) {
        float2 v = *(const float2*)&S[r * SS + 2 * lane];
        float m = fmaxf(v.x, v.y);
        #pragma unroll
        for (int off = 32; off > 0; off >>= 1) m = fmaxf(m, __shfl_xor(m, off));
        float e0 = __expf(v.x - m), e1 = __expf(v.y - m);
        float s = e0 + e1;
        #pragma unroll
        for (int off = 32; off > 0; off >>= 1) s += __shfl_xor(s, off);
        float inv = 1.0f / s;
        float2 o; o.x = e0 * inv; o.y = e1 * inv;
        *(float2*)&S[r * SS + 2 * lane] = o;
    }
    __syncthreads();

    // ---- PV (swapped): D[d = tj*16+quad*4+r][i = wave*16+l16]
    f32x4 oacc[4];
    #pragma unroll
    for (int j = 0; j < 4; j++)
        #pragma unroll
        for (int r = 0; r < 4; r++) oacc[j][r] = 0.f;

    #pragma unroll
    for (int k0 = 0; k0 < 128; k0 += 32) {
        int m = wave * 16 + l16;
        const float* p = &S[m * SS + k0 + quad * 8];
        f32x4 xa = *(const f32x4*)p;
        f32x4 xb = *(const f32x4*)(p + 4);
        bf16x8 af;
        af[0] = f2bf(xa[0]); af[1] = f2bf(xa[1]); af[2] = f2bf(xa[2]); af[3] = f2bf(xa[3]);
        af[4] = f2bf(xb[0]); af[5] = f2bf(xb[1]); af[6] = f2bf(xb[2]); af[7] = f2bf(xb[3]);
        #pragma unroll
        for (int tj = 0; tj < 4; tj++) {
            bf16x8 bfr = (k0 < 64)
                ? vpre[(k0 >> 5) * 4 + tj]
                : *(const bf16x8*)(vbase + (size_t)(tj * 16 + l16) * 128 + k0 + quad * 8);
            oacc[tj] = __builtin_amdgcn_mfma_f32_16x16x32_bf16(bfr, af, oacc[tj], 0, 0, 0);
        }
    }
    {
        int i = wave * 16 + l16;
        __hip_bfloat16* obase = O + (size_t)(g * 128 + i) * 512 + h * 64 + quad * 4;
        #pragma unroll
        for (int tj = 0; tj < 4; tj++) {
            bf16x4 ov;
            ov[0] = f2bf(oacc[tj][0]);
            ov[1] = f2bf(oacc[tj][1]);
            ov[2] = f2bf(oacc[tj][2]);
            ov[3] = f2bf(oacc[tj][3]);
            *(bf16x4*)(obase + tj * 16) = ov;
        }
    }
}

// ---------------------------------------------------------------------------
// Workspace layout (bytes). Edge-MLP tables packed CONTIGUOUS at WS_TAB
// (w1fragt 4KB | b1f 2KB | w2at 16KB = 22.5 KB) for one-shot LDS staging.
// xbf (pre-cast x) ALIASES O: live ranges [prep->mega] vs [attn->gemm1].
// ---------------------------------------------------------------------------
#define WS_WQKVT 0x0          // 1536*512 bf16 = 1.5 MB
#define WS_WOT   0x180000     // 512*512 bf16 = 0.5 MB -> ends 0x200000
#define WS_TAB   0x200000     // table block base (22.5 KB contiguous)
#define WS_W1FR  0x200000     // 4 KB
#define WS_B1F   0x201000     // 2 KB
#define WS_W2AT  0x201800     // 16 KB -> 0x205800
#define WS_B2F   0x205800     // 32 B
#define WS_Q     0x210000     // 8 MB ([g*8+h][i][64]) -> 0xA10000
#define WS_K     0xA10000     // 8 MB ([g*8+h][j][64]) -> 0x1210000
#define WS_VT    0x1210000    // 8 MB ([g*8+h][d][128]) -> 0x1A10000
#define WS_BIASE 0x1A10000    // 8 MB ([h][e] fp32) -> 0x2210000
#define WS_O     0x2210000    // 8 MB -> 0x2A10000 (aliased by xbf)
#define WS_XBF   WS_O

extern "C" void kernel_launch(void* const* d_in, const int* in_sizes, int n_in,
                              void* d_out, int out_size, void* d_ws, size_t ws_size,
                              hipStream_t stream) {
    const float* x    = (const float*)d_in[0];
    const int*   eidx = (const int*)d_in[1];
    const float* ea   = (const float*)d_in[2];
    // d_in[3] = batch, d_in[4] = n_g (unused; block structure is fixed)
    const float* Wq = (const float*)d_in[5];
    const float* bq = (const float*)d_in[6];
    const float* Wk = (const float*)d_in[7];
    const float* bk = (const float*)d_in[8];
    const float* Wv = (const float*)d_in[9];
    const float* bv = (const float*)d_in[10];
    const float* Wo = (const float*)d_in[11];
    const float* bo = (const float*)d_in[12];
    const float* W1 = (const float*)d_in[13];
    const float* b1 = (const float*)d_in[14];
    const float* W2 = (const float*)d_in[15];
    const float* b2 = (const float*)d_in[16];

    char* ws = (char*)d_ws;
    __hip_bfloat16* wqkvt   = (__hip_bfloat16*)(ws + WS_WQKVT);
    __hip_bfloat16* wot     = (__hip_bfloat16*)(ws + WS_WOT);
    __hip_bfloat16* w1fragt = (__hip_bfloat16*)(ws + WS_W1FR);
    float* b1f   = (float*)(ws + WS_B1F);
    __hip_bfloat16* w2at    = (__hip_bfloat16*)(ws + WS_W2AT);
    float* b2f   = (float*)(ws + WS_B2F);
    __hip_bfloat16* qbuf = (__hip_bfloat16*)(ws + WS_Q);
    __hip_bfloat16* kbuf = (__hip_bfloat16*)(ws + WS_K);
    __hip_bfloat16* vt  = (__hip_bfloat16*)(ws + WS_VT);
    float* biasE = (float*)(ws + WS_BIASE);
    __hip_bfloat16* O   = (__hip_bfloat16*)(ws + WS_O);
    __hip_bfloat16* xbf = (__hip_bfloat16*)(ws + WS_XBF);

    prep_kernel<<<257 + 2048, 256, 0, stream>>>(Wq, Wk, Wv, Wo, W1, b1, W2, b2,
                                                x, xbf,
                                                wqkvt, wot, w1fragt, b1f, w2at, b2f);
    mega_kernel<<<1280, 512, 0, stream>>>(
        xbf, wqkvt, bq, bk, bv, qbuf, kbuf, vt,
        ea, ws + WS_TAB, b2f, biasE);
    attn_kernel<<<GRAPHS * NHEADS, 512, 0, stream>>>(qbuf, kbuf, vt, biasE, eidx, O);
    gemm1_kernel<<<dim3(NNODES / 128, 512 / 64), 256, 0, stream>>>(
        O, wot, bo, (float*)d_out);
}